// Round 6
// baseline (174.514 us; speedup 1.0000x reference)
//
#include <hip/hip_runtime.h>
#include <hip/hip_bf16.h>

// Edge MLP via MFMA, round 6: src-bucket counting sort kept, pipeline fixed.
//  - hist: 2344 blocks, global atomics into memset-zeroed bins (r5's 16-block
//    LDS hist was 64 us / 0.5% occupancy -- the whole regression).
//  - hist fused into prep kernel (disjoint blockIdx ranges, independent work).
//  - sorted edge packed as int4{src,dst,orig} -> 1 store in scatter, 1 load in main.
//  - main: XCD-chunked swizzle (4688%8==0, bijective) so consecutive sorted
//    blocks (sharing src bins) land on the same XCD L2.
//  Determinism: per-edge output value/location independent of atomic order.

#define NEDGE 600000
#define NNODES 50000
#define DIN 128
#define DH 64
#define NBIN 4096        // bin = src >> 4  (16 nodes = 4 KB bf16 of rows)
#define BINSH 4
#define STRK 136
#define EBLK 2344        // ceil(600000/256)
#define HCVT 6250        // h-convert blocks
#define WCVT 8           // W1^T blocks
#define MAINB 4688       // ceil(600000/128)

typedef __attribute__((ext_vector_type(8))) short bf16x8;
typedef __attribute__((ext_vector_type(4))) float f32x4;
typedef __attribute__((ext_vector_type(4))) unsigned int u32x4;

static __device__ __forceinline__ short f2bf(float f) {
    __hip_bfloat16 hb = __float2bfloat16(f);
    return *reinterpret_cast<short*>(&hb);
}
static __device__ __forceinline__ float bflo(unsigned int w) {
    return __builtin_bit_cast(float, w << 16);
}
static __device__ __forceinline__ float bfhi(unsigned int w) {
    return __builtin_bit_cast(float, w & 0xffff0000u);
}

// ---- K1 fused: hofs blocks hist | then HCVT h->bf16 | then WCVT W1->W1^T ----
// hofs==0 disables the hist range; hcv==0 disables the h-convert range.
__global__ __launch_bounds__(256) void k1_hist_prep(
    const int* __restrict__ src, const float* __restrict__ h,
    const float* __restrict__ W1, int* __restrict__ bcnt,
    unsigned short* __restrict__ hbf, unsigned short* __restrict__ w1t,
    int hofs, int hcv)
{
    const int b = blockIdx.x;
    if (b < hofs) {
        int e = b * 256 + threadIdx.x;
        if (e < NEDGE) atomicAdd(&bcnt[((unsigned)src[e]) >> BINSH], 1);
    } else if (b < hofs + hcv) {
        int i = ((b - hofs) * 256 + threadIdx.x) * 4;
        f32x4 v = *reinterpret_cast<const f32x4*>(h + i);
        ushort4 o;
        o.x = (unsigned short)f2bf(v[0]);
        o.y = (unsigned short)f2bf(v[1]);
        o.z = (unsigned short)f2bf(v[2]);
        o.w = (unsigned short)f2bf(v[3]);
        *reinterpret_cast<ushort4*>(hbf + i) = o;
    } else {
        int j = ((b - hofs - hcv) * 256 + threadIdx.x) * 4;
        f32x4 w = *reinterpret_cast<const f32x4*>(W1 + j);
        int k = j >> 6, c = j & 63;
#pragma unroll
        for (int q = 0; q < 4; ++q)
            w1t[(c + q) * DIN + k] = (unsigned short)f2bf(w[q]);
    }
}

// ---- K2: exclusive scan of 4096 bins, 1 block x 1024 ----
__global__ __launch_bounds__(1024) void scan_kernel(
    const int* __restrict__ bcnt, int* __restrict__ cursor)
{
    __shared__ int ts[1024];
    const int t = threadIdx.x;
    int pre[4];
    int s = 0;
#pragma unroll
    for (int j = 0; j < 4; ++j) {
        pre[j] = s;
        s += bcnt[t * 4 + j];
    }
    ts[t] = s;
    __syncthreads();
    for (int off = 1; off < 1024; off <<= 1) {
        int v = (t >= off) ? ts[t - off] : 0;
        __syncthreads();
        ts[t] += v;
        __syncthreads();
    }
    int excl = (t > 0) ? ts[t - 1] : 0;
#pragma unroll
    for (int j = 0; j < 4; ++j) cursor[t * 4 + j] = excl + pre[j];
}

// ---- K3: scatter into packed int4{src,dst,orig,0} ----
__global__ __launch_bounds__(256) void scatter_kernel(
    const int* __restrict__ src, const int* __restrict__ dst,
    int* __restrict__ cursor, int4* __restrict__ ssd)
{
    int e = blockIdx.x * 256 + threadIdx.x;
    if (e >= NEDGE) return;
    int s = src[e], d = dst[e];
    int pos = atomicAdd(&cursor[((unsigned)s) >> BINSH], 1);
    ssd[pos] = make_int4(s, d, e, 0);
}

// ---- K4 main. MODE 0 = sorted (int4 + scatter store), 1 = identity order ----
template<int MODE>
__global__ __launch_bounds__(256, 4) void mlp_main(
    const unsigned short* __restrict__ hbf,
    const unsigned short* __restrict__ w1t,
    const int4* __restrict__ ssd,
    const int* __restrict__ src, const int* __restrict__ dst,
    const float* __restrict__ b1, const float* __restrict__ W2,
    const float* __restrict__ b2, float* __restrict__ out)
{
    __shared__ unsigned short Blds[DH * STRK];
#pragma unroll
    for (int j = 0; j < 4; ++j) {
        int i = (threadIdx.x + j * 256) * 8;
        int r = i >> 7, c = i & 127;
        const ushort4* ps = reinterpret_cast<const ushort4*>(w1t + i);
        ushort4 v0 = ps[0], v1 = ps[1];
        *reinterpret_cast<ushort4*>(&Blds[r * STRK + c]) = v0;
        *reinterpret_cast<ushort4*>(&Blds[r * STRK + c + 4]) = v1;
    }
    __syncthreads();

    const int tid = threadIdx.x;
    const int l = tid & 63;
    const int lr = l & 15;
    const int g = l >> 4;
    const unsigned kg = (unsigned)(g * 8);

    // XCD-chunked bijective swizzle: consecutive work-chunks on one XCD.
    const int work = (MODE == 0)
        ? (blockIdx.x & 7) * (MAINB / 8) + (blockIdx.x >> 3)
        : blockIdx.x;
    const int bpos = work * 128 + (tid >> 6) * 32;

    float bv[4]; float2 w2v[4];
#pragma unroll
    for (int n = 0; n < 4; ++n) {
        bv[n] = b1[n * 16 + lr];
        w2v[n] = *reinterpret_cast<const float2*>(W2 + (n * 16 + lr) * 2);
    }
    const float bb0 = b2[0], bb1 = b2[1];

#pragma unroll
    for (int m = 0; m < 2; ++m) {
        int p = bpos + m * 16 + lr;
        if (p >= NEDGE) p = NEDGE - 1;
        unsigned sa, da;
        if (MODE == 0) {
            int4 sd = ssd[p];
            sa = (unsigned)sd.x * (unsigned)DIN;
            da = (unsigned)sd.y * (unsigned)DIN;
        } else {
            sa = (unsigned)src[p] * (unsigned)DIN;
            da = (unsigned)dst[p] * (unsigned)DIN;
        }

        u32x4 S[4], D[4];
#pragma unroll
        for (int ks = 0; ks < 4; ++ks) {
            S[ks] = *reinterpret_cast<const u32x4*>(hbf + sa + ks * 32 + kg);
            D[ks] = *reinterpret_cast<const u32x4*>(hbf + da + ks * 32 + kg);
        }

        f32x4 acc[4];
#pragma unroll
        for (int n = 0; n < 4; ++n) acc[n] = (f32x4){bv[n], bv[n], bv[n], bv[n]};

#pragma unroll
        for (int ks = 0; ks < 4; ++ks) {
            bf16x8 A;
#pragma unroll
            for (int w = 0; w < 4; ++w) {
                A[2 * w]     = f2bf(bflo(S[ks][w]) * bflo(D[ks][w]));
                A[2 * w + 1] = f2bf(bfhi(S[ks][w]) * bfhi(D[ks][w]));
            }
#pragma unroll
            for (int n = 0; n < 4; ++n) {
                bf16x8 Bf = *reinterpret_cast<const bf16x8*>(
                    &Blds[(n * 16 + lr) * STRK + ks * 32 + kg]);
                acc[n] = __builtin_amdgcn_mfma_f32_16x16x32_bf16(A, Bf, acc[n], 0, 0, 0);
            }
        }

        float o0 = 0.f, o1 = 0.f;
#pragma unroll
        for (int r = 0; r < 4; ++r) {
            float p0 = 0.f, p1 = 0.f;
#pragma unroll
            for (int n = 0; n < 4; ++n) {
                float v = fmaxf(acc[n][r], 0.f);
                p0 = fmaf(v, w2v[n].x, p0);
                p1 = fmaf(v, w2v[n].y, p1);
            }
#pragma unroll
            for (int sh = 1; sh < 16; sh <<= 1) {
                p0 += __shfl_xor(p0, sh, 64);
                p1 += __shfl_xor(p1, sh, 64);
            }
            if (lr == r) { o0 = p0; o1 = p1; }
        }
        int epos = bpos + m * 16 + g * 4 + lr;          // C row = g*4 + reg
        if (lr < 4 && epos < NEDGE) {
            int oe = (MODE == 0) ? reinterpret_cast<const int*>(ssd)[epos * 4 + 2]
                                 : epos;
            float2 ov = make_float2(o0 + bb0, o1 + bb1);
            *reinterpret_cast<float2*>(out + (size_t)oe * 2) = ov;
        }
    }
}

// ---- tier-3 fallback: fp32 gather, global W1t ----
__global__ __launch_bounds__(256) void mlp_f32_fallback(
    const float* __restrict__ hf, const unsigned short* __restrict__ w1t,
    const float* __restrict__ b1, const float* __restrict__ W2,
    const float* __restrict__ b2, const int* __restrict__ src,
    const int* __restrict__ dst, float* __restrict__ out)
{
    const int tid = threadIdx.x;
    const int l = tid & 63, lr = l & 15, g = l >> 4;
    const unsigned kg = (unsigned)(g * 8);
    const int wbase = blockIdx.x * 64 + (tid >> 6) * 16;
    const unsigned e = (unsigned)(wbase + lr);
    const unsigned sa = (unsigned)src[e] * (unsigned)DIN;
    const unsigned da = (unsigned)dst[e] * (unsigned)DIN;
    f32x4 acc[4];
#pragma unroll
    for (int n = 0; n < 4; ++n) {
        float bvv = b1[n * 16 + lr];
        acc[n] = (f32x4){bvv, bvv, bvv, bvv};
    }
#pragma unroll
    for (int ks = 0; ks < 4; ++ks) {
        const float* ps = hf + sa + ks * 128 + g * 32;
        const float* pd = hf + da + ks * 128 + g * 32;
        f32x4 s0 = *reinterpret_cast<const f32x4*>(ps);
        f32x4 s1 = *reinterpret_cast<const f32x4*>(ps + 4);
        f32x4 d0 = *reinterpret_cast<const f32x4*>(pd);
        f32x4 d1 = *reinterpret_cast<const f32x4*>(pd + 4);
        bf16x8 A, B[4];
#pragma unroll
        for (int n = 0; n < 4; ++n)
            B[n] = *reinterpret_cast<const bf16x8*>(w1t + (n * 16 + lr) * DIN + ks * 32 + kg);
#pragma unroll
        for (int q = 0; q < 4; ++q) {
            A[q]     = f2bf(s0[q] * d0[q]);
            A[q + 4] = f2bf(s1[q] * d1[q]);
        }
#pragma unroll
        for (int n = 0; n < 4; ++n)
            acc[n] = __builtin_amdgcn_mfma_f32_16x16x32_bf16(A, B[n], acc[n], 0, 0, 0);
    }
    float2 w2v[4];
#pragma unroll
    for (int n = 0; n < 4; ++n)
        w2v[n] = *reinterpret_cast<const float2*>(W2 + (n * 16 + lr) * 2);
    const float bb0 = b2[0], bb1 = b2[1];
    float o0 = 0.f, o1 = 0.f;
#pragma unroll
    for (int r = 0; r < 4; ++r) {
        float p0 = 0.f, p1 = 0.f;
#pragma unroll
        for (int n = 0; n < 4; ++n) {
            float v = fmaxf(acc[n][r], 0.f);
            p0 = fmaf(v, w2v[n].x, p0);
            p1 = fmaf(v, w2v[n].y, p1);
        }
#pragma unroll
        for (int sh = 1; sh < 16; sh <<= 1) {
            p0 += __shfl_xor(p0, sh, 64);
            p1 += __shfl_xor(p1, sh, 64);
        }
        if (lr == r) { o0 = p0; o1 = p1; }
    }
    if (lr < 4) {
        int edge = wbase + g * 4 + lr;
        float2 ov = make_float2(o0 + bb0, o1 + bb1);
        *reinterpret_cast<float2*>(out + (size_t)edge * 2) = ov;
    }
}

extern "C" void kernel_launch(void* const* d_in, const int* in_sizes, int n_in,
                              void* d_out, int out_size, void* d_ws, size_t ws_size,
                              hipStream_t stream) {
    const float* h  = (const float*)d_in[0];
    const float* W1 = (const float*)d_in[1];
    const float* b1 = (const float*)d_in[2];
    const float* W2 = (const float*)d_in[3];
    const float* b2 = (const float*)d_in[4];
    const int* src  = (const int*)d_in[5];
    const int* dst  = (const int*)d_in[6];
    float* out = (float*)d_out;

    // ws layout (bytes)
    const size_t OFF_HBF  = 0;            // 12,800,000
    const size_t OFF_W1T  = 12800000;     // 16,384
    const size_t OFF_BCNT = 12816384;     // 16,384
    const size_t OFF_CUR  = 12832768;     // 16,384
    const size_t OFF_SSD  = 12849152;     // 9,600,000
    const size_t NEED_FULL = OFF_SSD + 9600000;   // 22,449,152
    const size_t NEED_BF   = OFF_BCNT;            // hbf + w1t only
    const size_t NEED_MIN  = 16384;

    char* ws = (char*)d_ws;

    if (ws_size >= NEED_FULL) {
        unsigned short* hbf = (unsigned short*)(ws + OFF_HBF);
        unsigned short* w1t = (unsigned short*)(ws + OFF_W1T);
        int* bcnt = (int*)(ws + OFF_BCNT);
        int* cur  = (int*)(ws + OFF_CUR);
        int4* ssd = (int4*)(ws + OFF_SSD);

        hipMemsetAsync(bcnt, 0, NBIN * sizeof(int), stream);
        k1_hist_prep<<<EBLK + HCVT + WCVT, 256, 0, stream>>>(
            src, h, W1, bcnt, hbf, w1t, EBLK, HCVT);
        scan_kernel<<<1, 1024, 0, stream>>>(bcnt, cur);
        scatter_kernel<<<EBLK, 256, 0, stream>>>(src, dst, cur, ssd);
        mlp_main<0><<<MAINB, 256, 0, stream>>>(hbf, w1t, ssd, nullptr, nullptr, b1, W2, b2, out);
    } else if (ws_size >= NEED_BF) {
        unsigned short* hbf = (unsigned short*)(ws + OFF_HBF);
        unsigned short* w1t = (unsigned short*)(ws + OFF_W1T);
        k1_hist_prep<<<HCVT + WCVT, 256, 0, stream>>>(
            src, h, W1, nullptr, hbf, w1t, 0, HCVT);   // no hist range
        mlp_main<1><<<MAINB, 256, 0, stream>>>(hbf, w1t, nullptr, src, dst, b1, W2, b2, out);
    } else if (ws_size >= NEED_MIN) {
        unsigned short* w1t = (unsigned short*)ws;
        k1_hist_prep<<<WCVT, 256, 0, stream>>>(
            src, h, W1, nullptr, nullptr, w1t, 0, 0);  // W1^T range only
        mlp_f32_fallback<<<NEDGE / 64, 256, 0, stream>>>(h, w1t, b1, W2, b2, src, dst, out);
    }
}

// Round 7
// 57.878 us; speedup vs baseline: 3.0152x; 3.0152x over previous
//
#include <hip/hip_runtime.h>
#include <hip/hip_bf16.h>

// Edge MLP via MFMA, round 7: sort abandoned (r5/r6 proved any 600k-atomic
// pass costs >=50us -- exceeds the locality saving). Attack gather latency via
// outstanding-miss product instead:
//   waves/SIMD (3, launch_bounds cap) x loads-in-flight/wave (16, all hoisted)
//   = 48 outstanding vmem/SIMD vs r3's ~12 (r3: ILP 8 but 1.5 waves/SIMD;
//   r4: 6 waves but VGPR=36 killed ILP -- service rate varied 1.0-1.6 TB/s
//   between them => latency-bound, not a fabric BW wall).
// Per wave: 32 edges (2 m-tiles), 16 u32x4 gathers issued up-front (64 VGPR),
// B-frags from LDS W1^T (vmem queue stays clear for gathers), m=0 compute
// overlaps m=1 loads (in-order vmcnt consumption). 2-kernel pipeline.

#define NEDGE 600000
#define NNODES 50000
#define DIN 128
#define DH 64
#define STRK 136       // LDS row stride (shorts): 272B -> conflict-benign b128
#define HCVT 6250      // h-convert blocks
#define WCVT 8         // W1^T blocks
#define MAINB 4688     // ceil(600000/128)

typedef __attribute__((ext_vector_type(8))) short bf16x8;
typedef __attribute__((ext_vector_type(4))) float f32x4;
typedef __attribute__((ext_vector_type(4))) unsigned int u32x4;

static __device__ __forceinline__ short f2bf(float f) {
    __hip_bfloat16 hb = __float2bfloat16(f);
    return *reinterpret_cast<short*>(&hb);
}
static __device__ __forceinline__ float bflo(unsigned int w) {
    return __builtin_bit_cast(float, w << 16);
}
static __device__ __forceinline__ float bfhi(unsigned int w) {
    return __builtin_bit_cast(float, w & 0xffff0000u);
}

// ---- prep: blocks [0,wofs) h->bf16 ; [wofs, wofs+WCVT) W1 -> W1^T bf16 ----
__global__ __launch_bounds__(256) void prep_kernel(
    const float* __restrict__ h, const float* __restrict__ W1,
    unsigned short* __restrict__ hbf, unsigned short* __restrict__ w1t, int wofs)
{
    const int b = blockIdx.x;
    if (b < wofs) {
        int i = (b * 256 + threadIdx.x) * 4;
        f32x4 v = *reinterpret_cast<const f32x4*>(h + i);
        ushort4 o;
        o.x = (unsigned short)f2bf(v[0]);
        o.y = (unsigned short)f2bf(v[1]);
        o.z = (unsigned short)f2bf(v[2]);
        o.w = (unsigned short)f2bf(v[3]);
        *reinterpret_cast<ushort4*>(hbf + i) = o;
    } else {
        int j = ((b - wofs) * 256 + threadIdx.x) * 4;
        f32x4 w = *reinterpret_cast<const f32x4*>(W1 + j);
        int k = j >> 6, c = j & 63;
#pragma unroll
        for (int q = 0; q < 4; ++q)
            w1t[(c + q) * DIN + k] = (unsigned short)f2bf(w[q]);
    }
}

// ---- main: per wave 32 edges; 16 gathers hoisted; LDS B-frags ----
__global__ __launch_bounds__(256, 3) void mlp_main(
    const unsigned short* __restrict__ hbf,
    const unsigned short* __restrict__ w1t,
    const int* __restrict__ src, const int* __restrict__ dst,
    const float* __restrict__ b1, const float* __restrict__ W2,
    const float* __restrict__ b2, float* __restrict__ out)
{
    __shared__ unsigned short Blds[DH * STRK];

    const int tid = threadIdx.x;
    const int l = tid & 63;
    const int lr = l & 15;        // edge row within m-tile / hid col
    const int g = l >> 4;         // k-group (8 shorts)
    const unsigned kg = (unsigned)(g * 8);
    const int bpos = blockIdx.x * 128 + (tid >> 6) * 32;

    // edge indices for the wave's two m-tiles (clamped; stores are guarded)
    int p0 = bpos + lr;      if (p0 >= NEDGE) p0 = NEDGE - 1;
    int p1 = bpos + 16 + lr; if (p1 >= NEDGE) p1 = NEDGE - 1;
    const unsigned sa0 = (unsigned)src[p0] * (unsigned)DIN;
    const unsigned da0 = (unsigned)dst[p0] * (unsigned)DIN;
    const unsigned sa1 = (unsigned)src[p1] * (unsigned)DIN;
    const unsigned da1 = (unsigned)dst[p1] * (unsigned)DIN;

    // ---- issue ALL 16 gather loads up-front (held in 64 VGPRs) ----
    u32x4 S0[4], D0[4], S1[4], D1[4];
#pragma unroll
    for (int ks = 0; ks < 4; ++ks) {
        S0[ks] = *reinterpret_cast<const u32x4*>(hbf + sa0 + ks * 32 + kg);
        D0[ks] = *reinterpret_cast<const u32x4*>(hbf + da0 + ks * 32 + kg);
    }
#pragma unroll
    for (int ks = 0; ks < 4; ++ks) {
        S1[ks] = *reinterpret_cast<const u32x4*>(hbf + sa1 + ks * 32 + kg);
        D1[ks] = *reinterpret_cast<const u32x4*>(hbf + da1 + ks * 32 + kg);
    }

    // ---- stage W1^T into LDS while gathers fly ----
#pragma unroll
    for (int j = 0; j < 4; ++j) {
        int i = (tid + j * 256) * 8;
        int r = i >> 7, c = i & 127;
        const ushort4* ps = reinterpret_cast<const ushort4*>(w1t + i);
        ushort4 v0 = ps[0], v1 = ps[1];
        *reinterpret_cast<ushort4*>(&Blds[r * STRK + c]) = v0;
        *reinterpret_cast<ushort4*>(&Blds[r * STRK + c + 4]) = v1;
    }
    __syncthreads();

    float bv[4]; float2 w2v[4];
#pragma unroll
    for (int n = 0; n < 4; ++n) {
        bv[n] = b1[n * 16 + lr];
        w2v[n] = *reinterpret_cast<const float2*>(W2 + (n * 16 + lr) * 2);
    }
    const float bb0 = b2[0], bb1 = b2[1];

    f32x4 acc[4];

    // ================= m-tile 0 =================
#pragma unroll
    for (int n = 0; n < 4; ++n) acc[n] = (f32x4){bv[n], bv[n], bv[n], bv[n]};
#pragma unroll
    for (int ks = 0; ks < 4; ++ks) {
        bf16x8 A;
#pragma unroll
        for (int w = 0; w < 4; ++w) {
            A[2 * w]     = f2bf(bflo(S0[ks][w]) * bflo(D0[ks][w]));
            A[2 * w + 1] = f2bf(bfhi(S0[ks][w]) * bfhi(D0[ks][w]));
        }
#pragma unroll
        for (int n = 0; n < 4; ++n) {
            bf16x8 Bf = *reinterpret_cast<const bf16x8*>(
                &Blds[(n * 16 + lr) * STRK + ks * 32 + kg]);
            acc[n] = __builtin_amdgcn_mfma_f32_16x16x32_bf16(A, Bf, acc[n], 0, 0, 0);
        }
    }
    {
        float o0 = 0.f, o1 = 0.f;
#pragma unroll
        for (int r = 0; r < 4; ++r) {
            float q0 = 0.f, q1 = 0.f;
#pragma unroll
            for (int n = 0; n < 4; ++n) {
                float v = fmaxf(acc[n][r], 0.f);
                q0 = fmaf(v, w2v[n].x, q0);
                q1 = fmaf(v, w2v[n].y, q1);
            }
#pragma unroll
            for (int sh = 1; sh < 16; sh <<= 1) {
                q0 += __shfl_xor(q0, sh, 64);
                q1 += __shfl_xor(q1, sh, 64);
            }
            if (lr == r) { o0 = q0; o1 = q1; }
        }
        int epos = bpos + g * 4 + lr;           // C row = g*4 + reg
        if (lr < 4 && epos < NEDGE) {
            float2 ov = make_float2(o0 + bb0, o1 + bb1);
            *reinterpret_cast<float2*>(out + (size_t)epos * 2) = ov;
        }
    }

    // ================= m-tile 1 =================
#pragma unroll
    for (int n = 0; n < 4; ++n) acc[n] = (f32x4){bv[n], bv[n], bv[n], bv[n]};
#pragma unroll
    for (int ks = 0; ks < 4; ++ks) {
        bf16x8 A;
#pragma unroll
        for (int w = 0; w < 4; ++w) {
            A[2 * w]     = f2bf(bflo(S1[ks][w]) * bflo(D1[ks][w]));
            A[2 * w + 1] = f2bf(bfhi(S1[ks][w]) * bfhi(D1[ks][w]));
        }
#pragma unroll
        for (int n = 0; n < 4; ++n) {
            bf16x8 Bf = *reinterpret_cast<const bf16x8*>(
                &Blds[(n * 16 + lr) * STRK + ks * 32 + kg]);
            acc[n] = __builtin_amdgcn_mfma_f32_16x16x32_bf16(A, Bf, acc[n], 0, 0, 0);
        }
    }
    {
        float o0 = 0.f, o1 = 0.f;
#pragma unroll
        for (int r = 0; r < 4; ++r) {
            float q0 = 0.f, q1 = 0.f;
#pragma unroll
            for (int n = 0; n < 4; ++n) {
                float v = fmaxf(acc[n][r], 0.f);
                q0 = fmaf(v, w2v[n].x, q0);
                q1 = fmaf(v, w2v[n].y, q1);
            }
#pragma unroll
            for (int sh = 1; sh < 16; sh <<= 1) {
                q0 += __shfl_xor(q0, sh, 64);
                q1 += __shfl_xor(q1, sh, 64);
            }
            if (lr == r) { o0 = q0; o1 = q1; }
        }
        int epos = bpos + 16 + g * 4 + lr;
        if (lr < 4 && epos < NEDGE) {
            float2 ov = make_float2(o0 + bb0, o1 + bb1);
            *reinterpret_cast<float2*>(out + (size_t)epos * 2) = ov;
        }
    }
}

// ---- minimal-ws fallback: fp32 gather, global W1t ----
__global__ __launch_bounds__(256) void mlp_f32_fallback(
    const float* __restrict__ hf, const unsigned short* __restrict__ w1t,
    const float* __restrict__ b1, const float* __restrict__ W2,
    const float* __restrict__ b2, const int* __restrict__ src,
    const int* __restrict__ dst, float* __restrict__ out)
{
    const int tid = threadIdx.x;
    const int l = tid & 63, lr = l & 15, g = l >> 4;
    const unsigned kg = (unsigned)(g * 8);
    const int wbase = blockIdx.x * 64 + (tid >> 6) * 16;
    const unsigned e = (unsigned)(wbase + lr);
    const unsigned sa = (unsigned)src[e] * (unsigned)DIN;
    const unsigned da = (unsigned)dst[e] * (unsigned)DIN;
    f32x4 acc[4];
#pragma unroll
    for (int n = 0; n < 4; ++n) {
        float bvv = b1[n * 16 + lr];
        acc[n] = (f32x4){bvv, bvv, bvv, bvv};
    }
#pragma unroll
    for (int ks = 0; ks < 4; ++ks) {
        const float* ps = hf + sa + ks * 128 + g * 32;
        const float* pd = hf + da + ks * 128 + g * 32;
        f32x4 s0 = *reinterpret_cast<const f32x4*>(ps);
        f32x4 s1 = *reinterpret_cast<const f32x4*>(ps + 4);
        f32x4 d0 = *reinterpret_cast<const f32x4*>(pd);
        f32x4 d1 = *reinterpret_cast<const f32x4*>(pd + 4);
        bf16x8 A, B[4];
#pragma unroll
        for (int n = 0; n < 4; ++n)
            B[n] = *reinterpret_cast<const bf16x8*>(w1t + (n * 16 + lr) * DIN + ks * 32 + kg);
#pragma unroll
        for (int q = 0; q < 4; ++q) {
            A[q]     = f2bf(s0[q] * d0[q]);
            A[q + 4] = f2bf(s1[q] * d1[q]);
        }
#pragma unroll
        for (int n = 0; n < 4; ++n)
            acc[n] = __builtin_amdgcn_mfma_f32_16x16x32_bf16(A, B[n], acc[n], 0, 0, 0);
    }
    float2 w2v[4];
#pragma unroll
    for (int n = 0; n < 4; ++n)
        w2v[n] = *reinterpret_cast<const float2*>(W2 + (n * 16 + lr) * 2);
    const float bb0 = b2[0], bb1 = b2[1];
    float o0 = 0.f, o1 = 0.f;
#pragma unroll
    for (int r = 0; r < 4; ++r) {
        float q0 = 0.f, q1 = 0.f;
#pragma unroll
        for (int n = 0; n < 4; ++n) {
            float v = fmaxf(acc[n][r], 0.f);
            q0 = fmaf(v, w2v[n].x, q0);
            q1 = fmaf(v, w2v[n].y, q1);
        }
#pragma unroll
        for (int sh = 1; sh < 16; sh <<= 1) {
            q0 += __shfl_xor(q0, sh, 64);
            q1 += __shfl_xor(q1, sh, 64);
        }
        if (lr == r) { o0 = q0; o1 = q1; }
    }
    if (lr < 4) {
        int edge = wbase + g * 4 + lr;
        float2 ov = make_float2(o0 + bb0, o1 + bb1);
        *reinterpret_cast<float2*>(out + (size_t)edge * 2) = ov;
    }
}

extern "C" void kernel_launch(void* const* d_in, const int* in_sizes, int n_in,
                              void* d_out, int out_size, void* d_ws, size_t ws_size,
                              hipStream_t stream) {
    const float* h  = (const float*)d_in[0];
    const float* W1 = (const float*)d_in[1];
    const float* b1 = (const float*)d_in[2];
    const float* W2 = (const float*)d_in[3];
    const float* b2 = (const float*)d_in[4];
    const int* src  = (const int*)d_in[5];
    const int* dst  = (const int*)d_in[6];
    float* out = (float*)d_out;

    const size_t OFF_W1T = (size_t)NNODES * DIN * 2;     // 12,800,000
    const size_t NEED_BF = OFF_W1T + (size_t)DH * DIN * 2;
    const size_t NEED_MIN = (size_t)DH * DIN * 2;

    char* ws = (char*)d_ws;

    if (ws_size >= NEED_BF) {
        unsigned short* hbf = (unsigned short*)ws;
        unsigned short* w1t = (unsigned short*)(ws + OFF_W1T);
        prep_kernel<<<HCVT + WCVT, 256, 0, stream>>>(h, W1, hbf, w1t, HCVT);
        mlp_main<<<MAINB, 256, 0, stream>>>(hbf, w1t, src, dst, b1, W2, b2, out);
    } else if (ws_size >= NEED_MIN) {
        unsigned short* w1t = (unsigned short*)ws;
        prep_kernel<<<WCVT, 256, 0, stream>>>(h, W1, nullptr, w1t, 0);
        mlp_f32_fallback<<<NEDGE / 64, 256, 0, stream>>>(h, w1t, b1, W2, b2, src, dst, out);
    }
}